// Round 5
// baseline (175.594 us; speedup 1.0000x reference)
//
#include <hip/hip_runtime.h>
#include <hip/hip_bf16.h>

#define B_ 8
#define T_ 2048
#define D_ 256
#define S_ 2048

// Kernel 1: dot[b,t] = <f[t], f[t+1]>, nsq[b,t] = <f[t], f[t]> in f64. One wave/row.
__global__ __launch_bounds__(256) void k_dotnsq(const float* __restrict__ fr,
                                                double* __restrict__ dotg,
                                                double* __restrict__ nsqg){
  int lane = threadIdx.x & 63;
  int w = threadIdx.x >> 6;
  int p = blockIdx.x * 4 + w;                 // p = b*T + t
  const float4* f4 = (const float4*)fr;
  float4 a = f4[(size_t)p * 64 + lane];
  double nsq = (double)a.x*a.x + (double)a.y*a.y + (double)a.z*a.z + (double)a.w*a.w;
  int t = p & (T_ - 1);
  double dt = 0.0;
  if (t < T_ - 1){
    float4 c = f4[(size_t)(p + 1) * 64 + lane];
    dt = (double)a.x*c.x + (double)a.y*c.y + (double)a.z*c.z + (double)a.w*c.w;
  }
  #pragma unroll
  for (int m = 32; m >= 1; m >>= 1){
    nsq += __shfl_xor(nsq, m, 64);
    dt  += __shfl_xor(dt,  m, 64);
  }
  if (lane == 0){
    nsqg[p] = nsq;
    dotg[p] = dt;
  }
}

// Kernel 2: per batch, f64, fully parallel: cos -> reduce min/max -> d -> p2 -> b
// -> block scan (per-thread 8 elems + wave shfl scan + cross-wave LDS).
__global__ __launch_bounds__(256) void k_boundary(const double* __restrict__ dotg,
                                                  const double* __restrict__ nsqg,
                                                  float* __restrict__ bcg,
                                                  double* __restrict__ numfrg){
  __shared__ double sd[T_];
  __shared__ double sb[T_];
  __shared__ double smin[4], smax[4], swv[4];
  int b = blockIdx.x, tid = threadIdx.x;
  int lane = tid & 63, w = tid >> 6;
  const double* dG = dotg + b * T_;
  const double* nG = nsqg + b * T_;
  for (int t = tid; t < T_ - 1; t += 256){
    double no = sqrt(nG[t]) * sqrt(nG[t + 1]);
    sd[t] = dG[t] / fmax(no, 1e-6);
  }
  __syncthreads();
  double mn = 1e300, mx = -1e300;
  for (int t = tid; t < T_ - 1; t += 256){ double v = sd[t]; mn = fmin(mn, v); mx = fmax(mx, v); }
  #pragma unroll
  for (int m = 32; m >= 1; m >>= 1){
    mn = fmin(mn, __shfl_xor(mn, m, 64));
    mx = fmax(mx, __shfl_xor(mx, m, 64));
  }
  if (lane == 0){ smin[w] = mn; smax[w] = mx; }
  __syncthreads();
  mn = fmin(fmin(smin[0], smin[1]), fmin(smin[2], smin[3]));
  mx = fmax(fmax(smax[0], smax[1]), fmax(smax[2], smax[3]));
  double inv = 1.0 / (mx - mn);
  for (int t = tid; t < T_ - 1; t += 256)
    sd[t] = 1.0 - (sd[t] - mn) * inv;
  __syncthreads();
  for (int t = tid; t < T_; t += 256){
    double v;
    if (t == 0) v = 1.0;
    else {
      int i = t - 1;                          // index into d (length T-1)
      if (i < 2 || i > T_ - 4) v = 0.0;       // p2[:, :2] = 0, p2[:, -2:] = 0
      else {
        double d0 = sd[i];
        double p2 = fmin(fmax(d0 - sd[i + 2], 0.0), fmax(d0 - sd[i - 2], 0.0));
        v = tanh(1e7 * p2);
      }
    }
    sb[t] = v;
  }
  __syncthreads();
  // scan: thread owns elements [8*tid, 8*tid+8). b vals are exactly {0,1}
  // (saturated tanh), so f64 partial sums are exact under any association.
  double loc[8]; double s = 0.0;
  #pragma unroll
  for (int j = 0; j < 8; ++j){ s += sb[8 * tid + j]; loc[j] = s; }
  double v = s;
  #pragma unroll
  for (int off = 1; off < 64; off <<= 1){
    double n = __shfl_up(v, (unsigned)off, 64);
    if (lane >= off) v += n;
  }
  if (lane == 63) swv[w] = v;
  __syncthreads();
  double wpre = 0.0;
  for (int i = 0; i < w; ++i) wpre += swv[i];
  double excl = wpre + v - s;
  #pragma unroll
  for (int j = 0; j < 8; ++j) bcg[b * T_ + 8 * tid + j] = (float)(excl + loc[j]);
  if (tid == 255) numfrg[b] = excl + s;
}

// Kernel 3: colsum[b,s] = sum_t (1 - tanh(10*|cc[s]-bc[t]|)).
// One block per 256-wide s-tile; internal t-tile loop with block-uniform overlap
// skip; register accumulate; ONE plain store. No atomics -> no memset needed.
__global__ __launch_bounds__(256) void k_colsum(const float* __restrict__ bcg,
                                                const double* __restrict__ numfrg,
                                                float* __restrict__ colsum){
  __shared__ float sbc[256];
  int tid = threadIdx.x;
  int b = blockIdx.y;
  int s = blockIdx.x * 256 + tid;
  double numfr = numfrg[b];
  float ccmin = (float)(blockIdx.x * 256 + 1);
  if ((double)ccmin > numfr) return;                 // whole s-tile invalid: k_pool never uses it
  float ccmax = fminf((float)(blockIdx.x * 256 + 256), (float)numfr);
  float cc = ((double)(s + 1) > numfr) ? 0.0f : (float)(s + 1);
  const float* bcb = bcg + b * T_;
  float acc = 0.0f;
  for (int t0 = 0; t0 < T_; t0 += 256){
    float bclo = bcb[t0], bchi = bcb[t0 + 255];      // block-uniform
    if (bclo - ccmax > 1.0f || ccmin - bchi > 1.0f) continue;  // terms <= 4.2e-9
    __syncthreads();
    sbc[tid] = bcb[t0 + tid];
    __syncthreads();
    #pragma unroll 4
    for (int i = 0; i < 256; ++i) acc += 1.0f - tanhf(10.0f * fabsf(cc - sbc[i]));
  }
  colsum[b * S_ + s] = acc;
}

// Kernel 4: segments[b,s,d] = sum_t mask[t,s]*frames[b,t,d], 16 s per block,
// 64-row frame tiles in LDS, monotone-bc tile skipping. f32 output.
__global__ __launch_bounds__(256) void k_pool(const float* __restrict__ fr,
                                              const float* __restrict__ bcg,
                                              const double* __restrict__ numfrg,
                                              const float* __restrict__ colsum,
                                              float* __restrict__ out){
  __shared__ float frT[64][256];   // 64 KB
  __shared__ float mT[64][16];     // 4 KB
  __shared__ float scol[16];
  int tid = threadIdx.x;
  int b = blockIdx.y;
  int s0 = blockIdx.x * 16;
  double numfr = numfrg[b];
  if (tid < 16) scol[tid] = colsum[b * S_ + s0 + tid];
  float acc[16];
  #pragma unroll
  for (int i = 0; i < 16; ++i) acc[i] = 0.0f;
  bool anyvalid = ((double)(s0 + 1) <= numfr);     // block-uniform
  if (anyvalid){
    const float* bcb = bcg + b * T_;
    float ccmin = (float)(s0 + 1);
    float ccmax = fminf((float)(s0 + 16), (float)numfr);
    for (int tt = 0; tt < T_ / 64; ++tt){
      int t0 = tt * 64;
      float bclo = bcb[t0], bchi = bcb[t0 + 63];   // bc monotone within tile
      if (bclo - ccmax > 1.0f || ccmin - bchi > 1.0f) continue;  // res <= 4.2e-9 there
      __syncthreads();
      const float4* src = (const float4*)(fr + ((size_t)(b * T_ + t0)) * D_);
      float4* dst = (float4*)&frT[0][0];
      #pragma unroll
      for (int i = 0; i < 16; ++i) dst[tid + i * 256] = src[tid + i * 256];
      #pragma unroll
      for (int k = 0; k < 4; ++k){
        int j = tid + k * 256;
        int tl = j & 63, sl = j >> 6;
        float m = 0.0f;
        if ((double)(s0 + sl + 1) <= numfr){
          float cs = (float)(s0 + sl + 1);
          float u = tanhf(10.0f * fabsf(cs - bcb[t0 + tl]));   // unres
          m = (1.0f - u) / (scol[sl] + u);
        }
        mT[tl][sl] = m;
      }
      __syncthreads();
      #pragma unroll 4
      for (int r = 0; r < 64; ++r){
        float f = frT[r][tid];
        const float4* mp = (const float4*)&mT[r][0];
        float4 m0 = mp[0], m1 = mp[1], m2 = mp[2], m3 = mp[3];
        acc[0]  += m0.x * f; acc[1]  += m0.y * f; acc[2]  += m0.z * f; acc[3]  += m0.w * f;
        acc[4]  += m1.x * f; acc[5]  += m1.y * f; acc[6]  += m1.z * f; acc[7]  += m1.w * f;
        acc[8]  += m2.x * f; acc[9]  += m2.y * f; acc[10] += m2.z * f; acc[11] += m2.w * f;
        acc[12] += m3.x * f; acc[13] += m3.y * f; acc[14] += m3.z * f; acc[15] += m3.w * f;
      }
    }
  }
  size_t base = ((size_t)b * S_ + s0) * D_ + tid;
  #pragma unroll
  for (int sl = 0; sl < 16; ++sl) out[base + (size_t)sl * D_] = acc[sl];
}

extern "C" void kernel_launch(void* const* d_in, const int* in_sizes, int n_in,
                              void* d_out, int out_size, void* d_ws, size_t ws_size,
                              hipStream_t stream) {
  const float* frames = (const float*)d_in[0];
  char* ws = (char*)d_ws;
  double* dotg   = (double*)ws;                               // B*T doubles
  double* nsqg   = (double*)(ws + B_ * T_ * 8);               // B*T doubles
  double* numfrg = (double*)(ws + 2 * B_ * T_ * 8);           // B doubles
  float*  bcg    = (float*)(ws + 2 * B_ * T_ * 8 + 64);       // B*T floats
  float*  colsum = (float*)(ws + 2 * B_ * T_ * 8 + 64 + B_ * T_ * 4); // B*S floats
  float* out = (float*)d_out;

  k_dotnsq<<<B_ * T_ / 4, 256, 0, stream>>>(frames, dotg, nsqg);
  k_boundary<<<B_, 256, 0, stream>>>(dotg, nsqg, bcg, numfrg);
  k_colsum<<<dim3(S_ / 256, B_), 256, 0, stream>>>(bcg, numfrg, colsum);
  k_pool<<<dim3(S_ / 16, B_), 256, 0, stream>>>(frames, bcg, numfrg, colsum, out);
}

// Round 6
// 56.490 us; speedup vs baseline: 3.1084x; 3.1084x over previous
//
#include <hip/hip_runtime.h>
#include <hip/hip_bf16.h>

#define B_ 8
#define T_ 2048
#define D_ 256
#define S_ 2048

// Kernel 1: dot[b,t] = <f[t], f[t+1]>, nsq[b,t] = <f[t], f[t]> in f64. One wave/row.
__global__ __launch_bounds__(256) void k_dotnsq(const float* __restrict__ fr,
                                                double* __restrict__ dotg,
                                                double* __restrict__ nsqg){
  int lane = threadIdx.x & 63;
  int w = threadIdx.x >> 6;
  int p = blockIdx.x * 4 + w;                 // p = b*T + t
  const float4* f4 = (const float4*)fr;
  float4 a = f4[(size_t)p * 64 + lane];
  double nsq = (double)a.x*a.x + (double)a.y*a.y + (double)a.z*a.z + (double)a.w*a.w;
  int t = p & (T_ - 1);
  double dt = 0.0;
  if (t < T_ - 1){
    float4 c = f4[(size_t)(p + 1) * 64 + lane];
    dt = (double)a.x*c.x + (double)a.y*c.y + (double)a.z*c.z + (double)a.w*c.w;
  }
  #pragma unroll
  for (int m = 32; m >= 1; m >>= 1){
    nsq += __shfl_xor(nsq, m, 64);
    dt  += __shfl_xor(dt,  m, 64);
  }
  if (lane == 0){
    nsqg[p] = nsq;
    dotg[p] = dt;
  }
}

// Kernel 2: per batch, f64, fully parallel: cos -> reduce min/max -> d -> p2 -> b
// -> block scan (per-thread 8 elems + wave shfl scan + cross-wave LDS).
__global__ __launch_bounds__(256) void k_boundary(const double* __restrict__ dotg,
                                                  const double* __restrict__ nsqg,
                                                  float* __restrict__ bcg,
                                                  double* __restrict__ numfrg){
  __shared__ double sd[T_];
  __shared__ double sb[T_];
  __shared__ double smin[4], smax[4], swv[4];
  int b = blockIdx.x, tid = threadIdx.x;
  int lane = tid & 63, w = tid >> 6;
  const double* dG = dotg + b * T_;
  const double* nG = nsqg + b * T_;
  for (int t = tid; t < T_ - 1; t += 256){
    double no = sqrt(nG[t]) * sqrt(nG[t + 1]);
    sd[t] = dG[t] / fmax(no, 1e-6);
  }
  __syncthreads();
  double mn = 1e300, mx = -1e300;
  for (int t = tid; t < T_ - 1; t += 256){ double v = sd[t]; mn = fmin(mn, v); mx = fmax(mx, v); }
  #pragma unroll
  for (int m = 32; m >= 1; m >>= 1){
    mn = fmin(mn, __shfl_xor(mn, m, 64));
    mx = fmax(mx, __shfl_xor(mx, m, 64));
  }
  if (lane == 0){ smin[w] = mn; smax[w] = mx; }
  __syncthreads();
  mn = fmin(fmin(smin[0], smin[1]), fmin(smin[2], smin[3]));
  mx = fmax(fmax(smax[0], smax[1]), fmax(smax[2], smax[3]));
  double inv = 1.0 / (mx - mn);
  for (int t = tid; t < T_ - 1; t += 256)
    sd[t] = 1.0 - (sd[t] - mn) * inv;
  __syncthreads();
  for (int t = tid; t < T_; t += 256){
    double v;
    if (t == 0) v = 1.0;
    else {
      int i = t - 1;                          // index into d (length T-1)
      if (i < 2 || i > T_ - 4) v = 0.0;       // p2[:, :2] = 0, p2[:, -2:] = 0
      else {
        double d0 = sd[i];
        double p2 = fmin(fmax(d0 - sd[i + 2], 0.0), fmax(d0 - sd[i - 2], 0.0));
        v = tanh(1e7 * p2);
      }
    }
    sb[t] = v;
  }
  __syncthreads();
  // scan: thread owns elements [8*tid, 8*tid+8). b vals are exactly {0,1}
  // (saturated tanh), so f64 partial sums are exact under any association.
  double loc[8]; double s = 0.0;
  #pragma unroll
  for (int j = 0; j < 8; ++j){ s += sb[8 * tid + j]; loc[j] = s; }
  double v = s;
  #pragma unroll
  for (int off = 1; off < 64; off <<= 1){
    double n = __shfl_up(v, (unsigned)off, 64);
    if (lane >= off) v += n;
  }
  if (lane == 63) swv[w] = v;
  __syncthreads();
  double wpre = 0.0;
  for (int i = 0; i < w; ++i) wpre += swv[i];
  double excl = wpre + v - s;
  #pragma unroll
  for (int j = 0; j < 8; ++j) bcg[b * T_ + 8 * tid + j] = (float)(excl + loc[j]);
  if (tid == 255) numfrg[b] = excl + s;
}

// Kernel 3: colsum[b,s] = sum_t (1 - tanh(10*|cc[s]-bc[t]|)).
// bc is monotone; only t with bc[t] in [cc-1, cc+1] contribute > 4.2e-9.
// Stage bc in LDS, binary-search the window start, accumulate ~10 terms.
// One thread per s; no atomics; invalid s written 0.
__global__ __launch_bounds__(256) void k_colsum(const float* __restrict__ bcg,
                                                const double* __restrict__ numfrg,
                                                float* __restrict__ colsum){
  __shared__ float sbc[T_];
  int tid = threadIdx.x;
  int b = blockIdx.y;
  int s = blockIdx.x * 256 + tid;
  const float4* src = (const float4*)(bcg + b * T_);
  float4* dst = (float4*)sbc;
  #pragma unroll
  for (int i = 0; i < T_ / 4 / 256; ++i) dst[tid + i * 256] = src[tid + i * 256];
  __syncthreads();
  double numfr = numfrg[b];
  float acc = 0.0f;
  if ((double)(s + 1) <= numfr){
    float cc = (float)(s + 1);
    float lov = cc - 1.0f, hiv = cc + 1.0f;
    int lo = 0, hi = T_;
    while (lo < hi){ int mid = (lo + hi) >> 1; if (sbc[mid] < lov) lo = mid + 1; else hi = mid; }
    for (int t = lo; t < T_ && sbc[t] <= hiv; ++t)
      acc += 1.0f - tanhf(10.0f * fabsf(cc - sbc[t]));
  }
  colsum[b * S_ + s] = acc;
}

// Kernel 4: segments[b,s,d] = sum_t mask[t,s]*frames[b,t,d], 16 s per block,
// 64-row frame tiles in LDS, monotone-bc tile skipping. f32 output.
__global__ __launch_bounds__(256) void k_pool(const float* __restrict__ fr,
                                              const float* __restrict__ bcg,
                                              const double* __restrict__ numfrg,
                                              const float* __restrict__ colsum,
                                              float* __restrict__ out){
  __shared__ float frT[64][256];   // 64 KB
  __shared__ float mT[64][16];     // 4 KB
  __shared__ float scol[16];
  int tid = threadIdx.x;
  int b = blockIdx.y;
  int s0 = blockIdx.x * 16;
  double numfr = numfrg[b];
  if (tid < 16) scol[tid] = colsum[b * S_ + s0 + tid];
  float acc[16];
  #pragma unroll
  for (int i = 0; i < 16; ++i) acc[i] = 0.0f;
  bool anyvalid = ((double)(s0 + 1) <= numfr);     // block-uniform
  if (anyvalid){
    const float* bcb = bcg + b * T_;
    float ccmin = (float)(s0 + 1);
    float ccmax = fminf((float)(s0 + 16), (float)numfr);
    for (int tt = 0; tt < T_ / 64; ++tt){
      int t0 = tt * 64;
      float bclo = bcb[t0], bchi = bcb[t0 + 63];   // bc monotone within tile
      if (bclo - ccmax > 1.0f || ccmin - bchi > 1.0f) continue;  // res <= 4.2e-9 there
      __syncthreads();
      const float4* src = (const float4*)(fr + ((size_t)(b * T_ + t0)) * D_);
      float4* dst = (float4*)&frT[0][0];
      #pragma unroll
      for (int i = 0; i < 16; ++i) dst[tid + i * 256] = src[tid + i * 256];
      #pragma unroll
      for (int k = 0; k < 4; ++k){
        int j = tid + k * 256;
        int tl = j & 63, sl = j >> 6;
        float m = 0.0f;
        if ((double)(s0 + sl + 1) <= numfr){
          float cs = (float)(s0 + sl + 1);
          float u = tanhf(10.0f * fabsf(cs - bcb[t0 + tl]));   // unres
          m = (1.0f - u) / (scol[sl] + u);
        }
        mT[tl][sl] = m;
      }
      __syncthreads();
      #pragma unroll 4
      for (int r = 0; r < 64; ++r){
        float f = frT[r][tid];
        const float4* mp = (const float4*)&mT[r][0];
        float4 m0 = mp[0], m1 = mp[1], m2 = mp[2], m3 = mp[3];
        acc[0]  += m0.x * f; acc[1]  += m0.y * f; acc[2]  += m0.z * f; acc[3]  += m0.w * f;
        acc[4]  += m1.x * f; acc[5]  += m1.y * f; acc[6]  += m1.z * f; acc[7]  += m1.w * f;
        acc[8]  += m2.x * f; acc[9]  += m2.y * f; acc[10] += m2.z * f; acc[11] += m2.w * f;
        acc[12] += m3.x * f; acc[13] += m3.y * f; acc[14] += m3.z * f; acc[15] += m3.w * f;
      }
    }
  }
  size_t base = ((size_t)b * S_ + s0) * D_ + tid;
  #pragma unroll
  for (int sl = 0; sl < 16; ++sl) out[base + (size_t)sl * D_] = acc[sl];
}

extern "C" void kernel_launch(void* const* d_in, const int* in_sizes, int n_in,
                              void* d_out, int out_size, void* d_ws, size_t ws_size,
                              hipStream_t stream) {
  const float* frames = (const float*)d_in[0];
  char* ws = (char*)d_ws;
  double* dotg   = (double*)ws;                               // B*T doubles
  double* nsqg   = (double*)(ws + B_ * T_ * 8);               // B*T doubles
  double* numfrg = (double*)(ws + 2 * B_ * T_ * 8);           // B doubles
  float*  bcg    = (float*)(ws + 2 * B_ * T_ * 8 + 64);       // B*T floats
  float*  colsum = (float*)(ws + 2 * B_ * T_ * 8 + 64 + B_ * T_ * 4); // B*S floats
  float* out = (float*)d_out;

  k_dotnsq<<<B_ * T_ / 4, 256, 0, stream>>>(frames, dotg, nsqg);
  k_boundary<<<B_, 256, 0, stream>>>(dotg, nsqg, bcg, numfrg);
  k_colsum<<<dim3(S_ / 256, B_), 256, 0, stream>>>(bcg, numfrg, colsum);
  k_pool<<<dim3(S_ / 16, B_), 256, 0, stream>>>(frames, bcg, numfrg, colsum, out);
}

// Round 7
// 38.212 us; speedup vs baseline: 4.5953x; 1.4783x over previous
//
#include <hip/hip_runtime.h>
#include <hip/hip_bf16.h>

#define B_ 8
#define T_ 2048
#define D_ 256
#define S_ 2048

// Kernel 1: dot[b,t] = <f[t], f[t+1]>, nsq[b,t] = <f[t], f[t]> in f64. One wave/row.
__global__ __launch_bounds__(256) void k_dotnsq(const float* __restrict__ fr,
                                                double* __restrict__ dotg,
                                                double* __restrict__ nsqg){
  int lane = threadIdx.x & 63;
  int w = threadIdx.x >> 6;
  int p = blockIdx.x * 4 + w;                 // p = b*T + t
  const float4* f4 = (const float4*)fr;
  float4 a = f4[(size_t)p * 64 + lane];
  double nsq = (double)a.x*a.x + (double)a.y*a.y + (double)a.z*a.z + (double)a.w*a.w;
  int t = p & (T_ - 1);
  double dt = 0.0;
  if (t < T_ - 1){
    float4 c = f4[(size_t)(p + 1) * 64 + lane];
    dt = (double)a.x*c.x + (double)a.y*c.y + (double)a.z*c.z + (double)a.w*c.w;
  }
  #pragma unroll
  for (int m = 32; m >= 1; m >>= 1){
    nsq += __shfl_xor(nsq, m, 64);
    dt  += __shfl_xor(dt,  m, 64);
  }
  if (lane == 0){
    nsqg[p] = nsq;
    dotg[p] = dt;
  }
}

// Kernel 2: per batch, f64, fully parallel: cos -> reduce min/max -> d -> p2 -> b
// -> block scan (per-thread 8 elems + wave shfl scan + cross-wave LDS).
__global__ __launch_bounds__(256) void k_boundary(const double* __restrict__ dotg,
                                                  const double* __restrict__ nsqg,
                                                  float* __restrict__ bcg,
                                                  double* __restrict__ numfrg){
  __shared__ double sd[T_];
  __shared__ double sb[T_];
  __shared__ double smin[4], smax[4], swv[4];
  int b = blockIdx.x, tid = threadIdx.x;
  int lane = tid & 63, w = tid >> 6;
  const double* dG = dotg + b * T_;
  const double* nG = nsqg + b * T_;
  for (int t = tid; t < T_ - 1; t += 256){
    double no = sqrt(nG[t]) * sqrt(nG[t + 1]);
    sd[t] = dG[t] / fmax(no, 1e-6);
  }
  __syncthreads();
  double mn = 1e300, mx = -1e300;
  for (int t = tid; t < T_ - 1; t += 256){ double v = sd[t]; mn = fmin(mn, v); mx = fmax(mx, v); }
  #pragma unroll
  for (int m = 32; m >= 1; m >>= 1){
    mn = fmin(mn, __shfl_xor(mn, m, 64));
    mx = fmax(mx, __shfl_xor(mx, m, 64));
  }
  if (lane == 0){ smin[w] = mn; smax[w] = mx; }
  __syncthreads();
  mn = fmin(fmin(smin[0], smin[1]), fmin(smin[2], smin[3]));
  mx = fmax(fmax(smax[0], smax[1]), fmax(smax[2], smax[3]));
  double inv = 1.0 / (mx - mn);
  for (int t = tid; t < T_ - 1; t += 256)
    sd[t] = 1.0 - (sd[t] - mn) * inv;
  __syncthreads();
  for (int t = tid; t < T_; t += 256){
    double v;
    if (t == 0) v = 1.0;
    else {
      int i = t - 1;                          // index into d (length T-1)
      if (i < 2 || i > T_ - 4) v = 0.0;       // p2[:, :2] = 0, p2[:, -2:] = 0
      else {
        double d0 = sd[i];
        double p2 = fmin(fmax(d0 - sd[i + 2], 0.0), fmax(d0 - sd[i - 2], 0.0));
        v = tanh(1e7 * p2);
      }
    }
    sb[t] = v;
  }
  __syncthreads();
  // scan: thread owns elements [8*tid, 8*tid+8). b vals are exactly {0,1}
  // (saturated tanh), so f64 partial sums are exact under any association.
  double loc[8]; double s = 0.0;
  #pragma unroll
  for (int j = 0; j < 8; ++j){ s += sb[8 * tid + j]; loc[j] = s; }
  double v = s;
  #pragma unroll
  for (int off = 1; off < 64; off <<= 1){
    double n = __shfl_up(v, (unsigned)off, 64);
    if (lane >= off) v += n;
  }
  if (lane == 63) swv[w] = v;
  __syncthreads();
  double wpre = 0.0;
  for (int i = 0; i < w; ++i) wpre += swv[i];
  double excl = wpre + v - s;
  #pragma unroll
  for (int j = 0; j < 8; ++j) bcg[b * T_ + 8 * tid + j] = (float)(excl + loc[j]);
  if (tid == 255) numfrg[b] = excl + s;
}

// Kernel 3 (fused colsum+pool): one WAVE per s. bc monotone => only t with
// bc[t] in [cc-1, cc+1] contribute > 4.2e-9 (same window as the r6 colsum,
// proven absmax 0.0). Pass 1 over window: scol = sum(res). Pass 2: acc +=
// m * frames[t], m = (1-u)/(scol+u). Lanes hold float4 of D; loads straight
// from global (frames are LLC-resident). Invalid s writes zeros (exact: ref
// res underflows to 0 in f32 there).
__global__ __launch_bounds__(256) void k_pool(const float* __restrict__ fr,
                                              const float* __restrict__ bcg,
                                              const double* __restrict__ numfrg,
                                              float* __restrict__ out){
  __shared__ float sbc[T_];
  int tid = threadIdx.x;
  int lane = tid & 63, w = tid >> 6;
  int b = blockIdx.y;
  int s = blockIdx.x * 4 + w;
  const float4* src4 = (const float4*)(bcg + b * T_);
  float4* dst4 = (float4*)sbc;
  #pragma unroll
  for (int i = 0; i < T_ / 4 / 256; ++i) dst4[tid + i * 256] = src4[tid + i * 256];
  __syncthreads();
  double numfr = numfrg[b];
  float4 acc = {0.0f, 0.0f, 0.0f, 0.0f};
  if ((double)(s + 1) <= numfr){
    float cc = (float)(s + 1);
    float lov = cc - 1.0f, hiv = cc + 1.0f;
    int lo = 0, hi = T_;
    while (lo < hi){ int mid = (lo + hi) >> 1; if (sbc[mid] < lov) lo = mid + 1; else hi = mid; }
    float scol = 0.0f;
    for (int t = lo; t < T_ && sbc[t] <= hiv; ++t)
      scol += 1.0f - tanhf(10.0f * fabsf(cc - sbc[t]));
    const float4* f4 = (const float4*)(fr + (size_t)b * T_ * D_);
    for (int t = lo; t < T_ && sbc[t] <= hiv; ++t){
      float u = tanhf(10.0f * fabsf(cc - sbc[t]));
      float m = (1.0f - u) / (scol + u);
      float4 f = f4[(size_t)t * 64 + lane];
      acc.x += m * f.x; acc.y += m * f.y; acc.z += m * f.z; acc.w += m * f.w;
    }
  }
  ((float4*)out)[((size_t)b * S_ + s) * 64 + lane] = acc;
}

extern "C" void kernel_launch(void* const* d_in, const int* in_sizes, int n_in,
                              void* d_out, int out_size, void* d_ws, size_t ws_size,
                              hipStream_t stream) {
  const float* frames = (const float*)d_in[0];
  char* ws = (char*)d_ws;
  double* dotg   = (double*)ws;                               // B*T doubles
  double* nsqg   = (double*)(ws + B_ * T_ * 8);               // B*T doubles
  double* numfrg = (double*)(ws + 2 * B_ * T_ * 8);           // B doubles
  float*  bcg    = (float*)(ws + 2 * B_ * T_ * 8 + 64);       // B*T floats
  float* out = (float*)d_out;

  k_dotnsq<<<B_ * T_ / 4, 256, 0, stream>>>(frames, dotg, nsqg);
  k_boundary<<<B_, 256, 0, stream>>>(dotg, nsqg, bcg, numfrg);
  k_pool<<<dim3(S_ / 4, B_), 256, 0, stream>>>(frames, bcg, numfrg, out);
}

// Round 8
// 33.551 us; speedup vs baseline: 5.2337x; 1.1389x over previous
//
#include <hip/hip_runtime.h>
#include <hip/hip_bf16.h>

#define B_ 8
#define T_ 2048
#define D_ 256
#define S_ 2048

// Kernel 1: cos[b,t] = <f[t],f[t+1]> / max(|f[t]||f[t+1]|, 1e-6), t in [0,T-2].
// One wave per row t; loads rows t and t+1 as float4/lane; 3 f32 wave reductions.
__global__ __launch_bounds__(256) void k_dotcos(const float* __restrict__ fr,
                                                float* __restrict__ cosg){
  int lane = threadIdx.x & 63;
  int w = threadIdx.x >> 6;
  int p = blockIdx.x * 4 + w;                 // p = b*T + t
  int t = p & (T_ - 1);
  const float4* f4 = (const float4*)fr;
  float4 a = f4[(size_t)p * 64 + lane];
  float na = a.x*a.x + a.y*a.y + a.z*a.z + a.w*a.w;
  float nc = 0.0f, dt = 0.0f;
  if (t < T_ - 1){
    float4 c = f4[(size_t)(p + 1) * 64 + lane];
    nc = c.x*c.x + c.y*c.y + c.z*c.z + c.w*c.w;
    dt = a.x*c.x + a.y*c.y + a.z*c.z + a.w*c.w;
  }
  #pragma unroll
  for (int m = 32; m >= 1; m >>= 1){
    na += __shfl_xor(na, m, 64);
    nc += __shfl_xor(nc, m, 64);
    dt += __shfl_xor(dt, m, 64);
  }
  if (lane == 0 && t < T_ - 1)
    cosg[p] = dt / fmaxf(sqrtf(na) * sqrtf(nc), 1e-6f);
}

// Kernel 2: per batch, f32, fully parallel: minmax(cos) -> d -> p2 -> b ->
// block scan (per-thread 8 elems + wave shfl scan + cross-wave LDS).
__global__ __launch_bounds__(256) void k_boundary(const float* __restrict__ cosg,
                                                  float* __restrict__ bcg,
                                                  float* __restrict__ numfrg){
  __shared__ float sd[T_];
  __shared__ float sb[T_];
  __shared__ float smin[4], smax[4], swv[4];
  int b = blockIdx.x, tid = threadIdx.x;
  int lane = tid & 63, w = tid >> 6;
  const float* cG = cosg + b * T_;
  for (int t = tid; t < T_ - 1; t += 256) sd[t] = cG[t];
  __syncthreads();
  float mn = 1e30f, mx = -1e30f;
  for (int t = tid; t < T_ - 1; t += 256){ float v = sd[t]; mn = fminf(mn, v); mx = fmaxf(mx, v); }
  #pragma unroll
  for (int m = 32; m >= 1; m >>= 1){
    mn = fminf(mn, __shfl_xor(mn, m, 64));
    mx = fmaxf(mx, __shfl_xor(mx, m, 64));
  }
  if (lane == 0){ smin[w] = mn; smax[w] = mx; }
  __syncthreads();
  mn = fminf(fminf(smin[0], smin[1]), fminf(smin[2], smin[3]));
  mx = fmaxf(fmaxf(smax[0], smax[1]), fmaxf(smax[2], smax[3]));
  float inv = 1.0f / (mx - mn);
  for (int t = tid; t < T_ - 1; t += 256)
    sd[t] = 1.0f - (sd[t] - mn) * inv;
  __syncthreads();
  for (int t = tid; t < T_; t += 256){
    float v;
    if (t == 0) v = 1.0f;
    else {
      int i = t - 1;                          // index into d (length T-1)
      if (i < 2 || i > T_ - 4) v = 0.0f;      // p2[:, :2] = 0, p2[:, -2:] = 0
      else {
        float d0 = sd[i];
        float p2 = fminf(fmaxf(d0 - sd[i + 2], 0.0f), fmaxf(d0 - sd[i - 2], 0.0f));
        v = tanhf(1e7f * p2);
      }
    }
    sb[t] = v;
  }
  __syncthreads();
  // scan: thread owns elements [8*tid, 8*tid+8). b vals are (near-)exactly {0,1}
  // so f32 partial sums are exact; downstream has ~1e-1 slack regardless.
  float loc[8]; float s = 0.0f;
  #pragma unroll
  for (int j = 0; j < 8; ++j){ s += sb[8 * tid + j]; loc[j] = s; }
  float v = s;
  #pragma unroll
  for (int off = 1; off < 64; off <<= 1){
    float n = __shfl_up(v, (unsigned)off, 64);
    if (lane >= off) v += n;
  }
  if (lane == 63) swv[w] = v;
  __syncthreads();
  float wpre = 0.0f;
  for (int i = 0; i < w; ++i) wpre += swv[i];
  float excl = wpre + v - s;
  #pragma unroll
  for (int j = 0; j < 8; ++j) bcg[b * T_ + 8 * tid + j] = excl + loc[j];
  if (tid == 255) numfrg[b] = excl + s;
}

// Kernel 3 (fused colsum+pool): one WAVE per s. bc monotone => only t with
// bc[t] in [cc-1, cc+1] contribute > 4.2e-9. Pass 1: scol = sum(res).
// Pass 2: acc += m * frames[t], m = (1-u)/(scol+u). Lanes hold float4 of D.
__global__ __launch_bounds__(256) void k_pool(const float* __restrict__ fr,
                                              const float* __restrict__ bcg,
                                              const float* __restrict__ numfrg,
                                              float* __restrict__ out){
  __shared__ float sbc[T_];
  int tid = threadIdx.x;
  int lane = tid & 63, w = tid >> 6;
  int b = blockIdx.y;
  int s = blockIdx.x * 4 + w;
  const float4* src4 = (const float4*)(bcg + b * T_);
  float4* dst4 = (float4*)sbc;
  #pragma unroll
  for (int i = 0; i < T_ / 4 / 256; ++i) dst4[tid + i * 256] = src4[tid + i * 256];
  __syncthreads();
  float numfr = numfrg[b];
  float4 acc = {0.0f, 0.0f, 0.0f, 0.0f};
  if ((float)(s + 1) <= numfr){
    float cc = (float)(s + 1);
    float lov = cc - 1.0f, hiv = cc + 1.0f;
    int lo = 0, hi = T_;
    while (lo < hi){ int mid = (lo + hi) >> 1; if (sbc[mid] < lov) lo = mid + 1; else hi = mid; }
    float scol = 0.0f;
    for (int t = lo; t < T_ && sbc[t] <= hiv; ++t)
      scol += 1.0f - tanhf(10.0f * fabsf(cc - sbc[t]));
    const float4* f4 = (const float4*)(fr + (size_t)b * T_ * D_);
    for (int t = lo; t < T_ && sbc[t] <= hiv; ++t){
      float u = tanhf(10.0f * fabsf(cc - sbc[t]));
      float m = (1.0f - u) / (scol + u);
      float4 f = f4[(size_t)t * 64 + lane];
      acc.x += m * f.x; acc.y += m * f.y; acc.z += m * f.z; acc.w += m * f.w;
    }
  }
  ((float4*)out)[((size_t)b * S_ + s) * 64 + lane] = acc;
}

extern "C" void kernel_launch(void* const* d_in, const int* in_sizes, int n_in,
                              void* d_out, int out_size, void* d_ws, size_t ws_size,
                              hipStream_t stream) {
  const float* frames = (const float*)d_in[0];
  float* ws = (float*)d_ws;
  float* cosg   = ws;                    // B*T
  float* bcg    = ws + B_ * T_;          // B*T
  float* numfrg = ws + 2 * B_ * T_;      // B
  float* out = (float*)d_out;

  k_dotcos<<<B_ * T_ / 4, 256, 0, stream>>>(frames, cosg);
  k_boundary<<<B_, 256, 0, stream>>>(cosg, bcg, numfrg);
  k_pool<<<dim3(S_ / 4, B_), 256, 0, stream>>>(frames, bcg, numfrg, out);
}